// Round 2
// baseline (437.809 us; speedup 1.0000x reference)
//
#include <hip/hip_runtime.h>

#define NN    16384
#define HD    128
#define G4    512
#define KST   16
#define NRELS 3

using bf16x8 = __attribute__((ext_vector_type(8))) __bf16;
using f32x4  = __attribute__((ext_vector_type(4))) float;
using u16x8  = __attribute__((ext_vector_type(8))) unsigned short;

static __device__ __forceinline__ unsigned short f2bf_bits(float f) {
    unsigned u = __builtin_bit_cast(unsigned, f);
    u += 0x7fffu + ((u >> 16) & 1u);   // RNE
    return (unsigned short)(u >> 16);
}
static __device__ __forceinline__ float bf2f(unsigned short b) {
    unsigned u = ((unsigned)b) << 16;
    return __builtin_bit_cast(float, u);
}
static __device__ __forceinline__ f32x4 f4splat(float v) {
    f32x4 r; r[0] = v; r[1] = v; r[2] = v; r[3] = v; return r;
}
// split v = hi + lo (both bf16); residual is (near-)exact in f32
static __device__ __forceinline__ void splitf(float v, unsigned short& h, unsigned short& l) {
    h = f2bf_bits(v);
    l = f2bf_bits(v - bf2f(h));
}
static __device__ __forceinline__ void load8split(const float* p, bf16x8& hi, bf16x8& lo) {
    const float4 a = ((const float4*)p)[0];
    const float4 b = ((const float4*)p)[1];
    const float vs[8] = {a.x, a.y, a.z, a.w, b.x, b.y, b.z, b.w};
    u16x8 uh, ul;
#pragma unroll
    for (int i = 0; i < 8; ++i) {
        unsigned short hh, ll;
        splitf(vs[i], hh, ll);
        uh[i] = hh; ul[i] = ll;
    }
    hi = __builtin_bit_cast(bf16x8, uh);
    lo = __builtin_bit_cast(bf16x8, ul);
}
static __device__ __forceinline__ bf16x8 load8bf(const float* p) {
    const float4 a = ((const float4*)p)[0];
    const float4 b = ((const float4*)p)[1];
    u16x8 u;
    u[0] = f2bf_bits(a.x); u[1] = f2bf_bits(a.y); u[2] = f2bf_bits(a.z); u[3] = f2bf_bits(a.w);
    u[4] = f2bf_bits(b.x); u[5] = f2bf_bits(b.y); u[6] = f2bf_bits(b.z); u[7] = f2bf_bits(b.w);
    return __builtin_bit_cast(bf16x8, u);
}
static __device__ __forceinline__ f32x4 mfma16(bf16x8 a, bf16x8 b, f32x4 c) {
    return __builtin_amdgcn_mfma_f32_16x16x32_bf16(a, b, c, 0, 0, 0);
}
static __device__ __forceinline__ float sigm(float x) {
    return __builtin_amdgcn_rcpf(1.0f + __expf(-x));
}
static __device__ __forceinline__ float tanh_(float x) {
    return 2.0f * __builtin_amdgcn_rcpf(1.0f + __expf(-2.0f * x)) - 1.0f;
}

// ---------------------------------------------------------------------------
// C[row,col] = A[row,:] @ W[r][col,:]^T (+bias[r][col]), split-bf16 (fp32-acc)
// MODE 0: f32 out [row*OUTC+col]                 (tc = conn @ trans.T)
// MODE 1: f32 out, gate-quad packed              (xW, full-precision path)
// MODE 2: bf16 out, gate-quad packed             (xW, small-ws fallback)
// quad offset = (r*NN+row)*512 + (col&127)*4 + (col>>7)
// ---------------------------------------------------------------------------
template <int OUTC, int MODE>
__global__ __launch_bounds__(512, 2) void gemm_rt(
    const float* __restrict__ A, const float* __restrict__ W,
    const float* __restrict__ bias, void* __restrict__ outp)
{
    constexpr int CW = OUTC / 8;
    constexpr int CT = CW / 16;
    const int tid = threadIdx.x;
    const int w = tid >> 6, lane = tid & 63;
    const int g = lane >> 4, m = lane & 15;
    const int n0 = blockIdx.x * 64;
    const int r = blockIdx.y;
    const float* Wr = W + (size_t)r * OUTC * HD;

    f32x4 acc[4][CT];
#pragma unroll
    for (int rt = 0; rt < 4; ++rt)
#pragma unroll
        for (int ct = 0; ct < CT; ++ct) acc[rt][ct] = f4splat(0.0f);

#pragma unroll
    for (int kc = 0; kc < 4; ++kc) {
        bf16x8 ah[4], al[4];
#pragma unroll
        for (int rt = 0; rt < 4; ++rt)
            load8split(A + (size_t)(n0 + rt * 16 + m) * HD + kc * 32 + 8 * g, ah[rt], al[rt]);
        bf16x8 bh[CT], bl[CT];
#pragma unroll
        for (int ct = 0; ct < CT; ++ct)
            load8split(Wr + (size_t)(w * CW + ct * 16 + m) * HD + kc * 32 + 8 * g, bh[ct], bl[ct]);
#pragma unroll
        for (int rt = 0; rt < 4; ++rt)
#pragma unroll
            for (int ct = 0; ct < CT; ++ct) {
                acc[rt][ct] = mfma16(ah[rt], bh[ct], acc[rt][ct]);
                acc[rt][ct] = mfma16(al[rt], bh[ct], acc[rt][ct]);
                acc[rt][ct] = mfma16(ah[rt], bl[ct], acc[rt][ct]);
            }
    }

#pragma unroll
    for (int rt = 0; rt < 4; ++rt)
#pragma unroll
        for (int ct = 0; ct < CT; ++ct) {
            const int col = w * CW + ct * 16 + m;
            const float bv = bias ? bias[r * OUTC + col] : 0.0f;
#pragma unroll
            for (int e = 0; e < 4; ++e) {
                const int row = n0 + rt * 16 + 4 * g + e;
                const float v = acc[rt][ct][e] + bv;
                if constexpr (MODE == 0) {
                    ((float*)outp)[(size_t)row * OUTC + col] = v;
                } else if constexpr (MODE == 1) {
                    ((float*)outp)[((size_t)r * NN + row) * G4 + (size_t)(col & 127) * 4 + (col >> 7)] = v;
                } else {
                    ((unsigned short*)outp)[((size_t)r * NN + row) * G4 + (size_t)(col & 127) * 4 + (col >> 7)] =
                        f2bf_bits(v);
                }
            }
        }
}

// ---------------------------------------------------------------------------
// 64 nodes/block, 3 relations sequentially. h kept as bf16 hi+lo pair in LDS
// (XOR-swizzled); c in f32 registers; gates accumulate f32 from f32 (or bf16)
// xW gather + split-h MFMA recurrence. Epilogue fc in split-bf16.
// ---------------------------------------------------------------------------
template <bool XWF32, bool XF32>
__global__ __launch_bounds__(512, 2) void lstm_kernel(
    const float* __restrict__ x, const int* __restrict__ nbr,
    const float* __restrict__ Whh, const float* __restrict__ fcs,
    const float* __restrict__ fcn, const float* __restrict__ bias,
    const void* __restrict__ xWv, void* __restrict__ Xoutv)
{
    __shared__ unsigned short h_hi[64 * HD];   // [row][col ^ ((row&7)<<3)]
    __shared__ unsigned short h_lo[64 * HD];
    __shared__ int idx_lds[64 * KST];

    const int tid = threadIdx.x;
    const int w = tid >> 6, lane = tid & 63;
    const int g = lane >> 4, m = lane & 15;
    const int n0 = blockIdx.x * 64;

    for (int r = 0; r < NRELS; ++r) {
        for (int i = tid; i < 64 * KST; i += 512)
            idx_lds[i] = nbr[(size_t)r * NN * KST + (size_t)(n0 + (i >> 4)) * KST + (i & 15)];

        // Whh B-fragments: wave w owns gate cols q*128 + w*16 + m
        bf16x8 bw[4][4];
        const float* whr = Whh + (size_t)r * G4 * HD;
#pragma unroll
        for (int q = 0; q < 4; ++q)
#pragma unroll
            for (int kc = 0; kc < 4; ++kc)
                bw[q][kc] = load8bf(whr + (size_t)(q * 128 + w * 16 + m) * HD + kc * 32 + 8 * g);

        float cst[4][4];
#pragma unroll
        for (int rt = 0; rt < 4; ++rt)
#pragma unroll
            for (int e = 0; e < 4; ++e) cst[rt][e] = 0.0f;

        __syncthreads();   // idx_lds ready

        for (int t = 0; t < KST; ++t) {
            // acc init = gathered xW quads (i,f,g,o for hid col w*16+m)
            f32x4 acc[4][4];
#pragma unroll
            for (int rt = 0; rt < 4; ++rt)
#pragma unroll
                for (int e = 0; e < 4; ++e) {
                    const int rl = rt * 16 + 4 * g + e;
                    const int nidx = idx_lds[rl * KST + t];
                    if constexpr (XWF32) {
                        const float4 q = *(const float4*)((const float*)xWv +
                            ((size_t)r * NN + nidx) * G4 + (size_t)(w * 16 + m) * 4);
                        acc[rt][0][e] = q.x; acc[rt][1][e] = q.y;
                        acc[rt][2][e] = q.z; acc[rt][3][e] = q.w;
                    } else {
                        const ushort4 q = *(const ushort4*)((const unsigned short*)xWv +
                            ((size_t)r * NN + nidx) * G4 + (size_t)(w * 16 + m) * 4);
                        acc[rt][0][e] = bf2f(q.x); acc[rt][1][e] = bf2f(q.y);
                        acc[rt][2][e] = bf2f(q.z); acc[rt][3][e] = bf2f(q.w);
                    }
                }

            if (t > 0) {
#pragma unroll
                for (int kc = 0; kc < 4; ++kc) {
                    bf16x8 a_hi[4], a_lo[4];
#pragma unroll
                    for (int rt = 0; rt < 4; ++rt) {
                        const int row = rt * 16 + m;
                        const int off = row * HD + ((kc * 32 + 8 * g) ^ ((row & 7) << 3));
                        a_hi[rt] = *(const bf16x8*)&h_hi[off];
                        a_lo[rt] = *(const bf16x8*)&h_lo[off];
                    }
#pragma unroll
                    for (int rt = 0; rt < 4; ++rt)
#pragma unroll
                        for (int q = 0; q < 4; ++q) {
                            acc[rt][q] = mfma16(a_hi[rt], bw[q][kc], acc[rt][q]);
                            acc[rt][q] = mfma16(a_lo[rt], bw[q][kc], acc[rt][q]);
                        }
                }
            }

            // elementwise LSTM cell (gate order i,f,g,o)
            float hf[4][4];
#pragma unroll
            for (int rt = 0; rt < 4; ++rt)
#pragma unroll
                for (int e = 0; e < 4; ++e) {
                    const float iv = sigm(acc[rt][0][e]);
                    const float fv = sigm(acc[rt][1][e]);
                    const float gv = tanh_(acc[rt][2][e]);
                    const float ov = sigm(acc[rt][3][e]);
                    const float cn = fv * cst[rt][e] + iv * gv;
                    cst[rt][e] = cn;
                    hf[rt][e] = ov * tanh_(cn);
                }

            __syncthreads();   // all A-reads of this step done
#pragma unroll
            for (int rt = 0; rt < 4; ++rt)
#pragma unroll
                for (int e = 0; e < 4; ++e) {
                    const int row = rt * 16 + 4 * g + e;
                    const int col = w * 16 + m;
                    const int off = row * HD + (col ^ ((row & 7) << 3));
                    unsigned short hh, ll;
                    splitf(hf[rt][e], hh, ll);
                    h_hi[off] = hh;
                    h_lo[off] = ll;
                }
            __syncthreads();   // h ready for next step
        }

        // ---- FC + leaky-relu: wave w -> row tile (w&3), col half (w>>2)
        {
            const int rt = w & 3;
            const int cth = (w >> 2) * 64;
            const float* fsr = fcs + (size_t)r * HD * HD;
            const float* fnr = fcn + (size_t)r * HD * HD;
            f32x4 oacc[4];
#pragma unroll
            for (int i = 0; i < 4; ++i)
                oacc[i] = f4splat(bias[r * HD + cth + i * 16 + m]);
#pragma unroll
            for (int kc = 0; kc < 4; ++kc) {
                const int row = rt * 16 + m;
                bf16x8 ax_hi, ax_lo;
                load8split(x + (size_t)(n0 + row) * HD + kc * 32 + 8 * g, ax_hi, ax_lo);
                const int off = row * HD + ((kc * 32 + 8 * g) ^ ((row & 7) << 3));
                const bf16x8 ah_hi = *(const bf16x8*)&h_hi[off];
                const bf16x8 ah_lo = *(const bf16x8*)&h_lo[off];
#pragma unroll
                for (int i = 0; i < 4; ++i) {
                    bf16x8 bs_hi, bs_lo, bn_hi, bn_lo;
                    load8split(fsr + (size_t)(cth + i * 16 + m) * HD + kc * 32 + 8 * g, bs_hi, bs_lo);
                    load8split(fnr + (size_t)(cth + i * 16 + m) * HD + kc * 32 + 8 * g, bn_hi, bn_lo);
                    oacc[i] = mfma16(ax_hi, bs_hi, oacc[i]);
                    oacc[i] = mfma16(ax_lo, bs_hi, oacc[i]);
                    oacc[i] = mfma16(ax_hi, bs_lo, oacc[i]);
                    oacc[i] = mfma16(ah_hi, bn_hi, oacc[i]);
                    oacc[i] = mfma16(ah_lo, bn_hi, oacc[i]);
                    oacc[i] = mfma16(ah_hi, bn_lo, oacc[i]);
                }
            }
#pragma unroll
            for (int i = 0; i < 4; ++i)
#pragma unroll
                for (int e = 0; e < 4; ++e) {
                    const int row = rt * 16 + 4 * g + e;
                    const int col = cth + i * 16 + m;
                    float v = oacc[i][e];
                    v = v > 0.0f ? v : 0.01f * v;
                    const size_t o = ((size_t)(n0 + row) * NRELS + r) * HD + col;
                    if constexpr (XF32) ((float*)Xoutv)[o] = v;
                    else ((unsigned short*)Xoutv)[o] = f2bf_bits(v);
                }
        }
        __syncthreads();   // protect h/idx before next relation
    }
}

// ---------------------------------------------------------------------------
// attention: one wave per node; softmax over 3 relations, f32 throughout
// ---------------------------------------------------------------------------
template <bool XF32>
__global__ __launch_bounds__(256) void attn_kernel(
    const void* __restrict__ Xv, const float* __restrict__ tc,
    float* __restrict__ out)
{
    const int wv = blockIdx.x * (blockDim.x >> 6) + (threadIdx.x >> 6);
    const int lane = threadIdx.x & 63;
    if (wv >= NN) return;
    const size_t nb = (size_t)wv;

    const float t0 = tc[nb * HD + lane];
    const float t1 = tc[nb * HD + 64 + lane];
    float x0[3], x1[3], sc[3];
#pragma unroll
    for (int r = 0; r < 3; ++r) {
        if constexpr (XF32) {
            x0[r] = ((const float*)Xv)[(nb * 3 + r) * HD + lane];
            x1[r] = ((const float*)Xv)[(nb * 3 + r) * HD + 64 + lane];
        } else {
            x0[r] = bf2f(((const unsigned short*)Xv)[(nb * 3 + r) * HD + lane]);
            x1[r] = bf2f(((const unsigned short*)Xv)[(nb * 3 + r) * HD + 64 + lane]);
        }
        float p = x0[r] * t0 + x1[r] * t1;
#pragma unroll
        for (int off = 32; off >= 1; off >>= 1)
            p += __shfl_xor(p, off, 64);
        sc[r] = p;
    }
    const float mx = fmaxf(sc[0], fmaxf(sc[1], sc[2]));
    const float e0 = __expf(sc[0] - mx), e1 = __expf(sc[1] - mx), e2 = __expf(sc[2] - mx);
    const float inv = __builtin_amdgcn_rcpf(e0 + e1 + e2);
    const float a0 = e0 * inv, a1 = e1 * inv, a2 = e2 * inv;
    out[nb * HD + lane]      = a0 * x0[0] + a1 * x0[1] + a2 * x0[2];
    out[nb * HD + 64 + lane] = a0 * x1[0] + a1 * x1[1] + a2 * x1[2];
}

extern "C" void kernel_launch(void* const* d_in, const int* in_sizes, int n_in,
                              void* d_out, int out_size, void* d_ws, size_t ws_size,
                              hipStream_t stream)
{
    const float* x     = (const float*)d_in[0];
    const float* conn  = (const float*)d_in[1];
    const int*   nbr   = (const int*)d_in[2];
    const float* trans = (const float*)d_in[3];
    const float* Wih   = (const float*)d_in[4];
    const float* Whh   = (const float*)d_in[5];
    const float* blstm = (const float*)d_in[6];
    const float* fcs   = (const float*)d_in[7];
    const float* fcn   = (const float*)d_in[8];
    const float* bias  = (const float*)d_in[9];
    float* out = (float*)d_out;

    const size_t TC_B   = (size_t)NN * HD * 4;               //   8.4 MB
    const size_t XW32_B = (size_t)NRELS * NN * G4 * 4;       // 100.7 MB
    const size_t XW16_B = (size_t)NRELS * NN * G4 * 2;       //  50.3 MB
    const size_t XO32_B = (size_t)NN * NRELS * HD * 4;       //  25.2 MB
    const size_t XO16_B = (size_t)NN * NRELS * HD * 2;       //  12.6 MB

    const bool full = ws_size >= XW32_B + TC_B + XO32_B;     // 134.2 MB
    if (!full && ws_size < XW16_B + TC_B + XO16_B) return;   // 71.3 MB floor

    char* wsb = (char*)d_ws;
    const size_t xw_b = full ? XW32_B : XW16_B;
    void*  xW = (void*)wsb;
    float* tc = (float*)(wsb + xw_b);
    void*  Xo = (void*)(wsb + xw_b + TC_B);

    if (full)
        gemm_rt<512, 1><<<dim3(NN / 64, NRELS), 512, 0, stream>>>(x, Wih, blstm, xW);
    else
        gemm_rt<512, 2><<<dim3(NN / 64, NRELS), 512, 0, stream>>>(x, Wih, blstm, xW);
    gemm_rt<128, 0><<<dim3(NN / 64, 1), 512, 0, stream>>>(conn, trans, nullptr, (void*)tc);
    if (full) {
        lstm_kernel<true, true><<<dim3(NN / 64), 512, 0, stream>>>(x, nbr, Whh, fcs, fcn, bias, xW, Xo);
        attn_kernel<true><<<dim3(NN / 4), 256, 0, stream>>>(Xo, tc, out);
    } else {
        lstm_kernel<false, false><<<dim3(NN / 64), 512, 0, stream>>>(x, nbr, Whh, fcs, fcn, bias, xW, Xo);
        attn_kernel<false><<<dim3(NN / 4), 256, 0, stream>>>(Xo, tc, out);
    }
}

// Round 3
// 405.256 us; speedup vs baseline: 1.0803x; 1.0803x over previous
//
#include <hip/hip_runtime.h>

#define NN    16384
#define HD    128
#define G4    512
#define KST   16
#define NRELS 3

using bf16x8 = __attribute__((ext_vector_type(8))) __bf16;
using f32x4  = __attribute__((ext_vector_type(4))) float;
using u16x8  = __attribute__((ext_vector_type(8))) unsigned short;

static __device__ __forceinline__ unsigned short f2bf_bits(float f) {
    unsigned u = __builtin_bit_cast(unsigned, f);
    u += 0x7fffu + ((u >> 16) & 1u);   // RNE
    return (unsigned short)(u >> 16);
}
static __device__ __forceinline__ float bf2f(unsigned short b) {
    unsigned u = ((unsigned)b) << 16;
    return __builtin_bit_cast(float, u);
}
static __device__ __forceinline__ f32x4 f4splat(float v) {
    f32x4 r; r[0] = v; r[1] = v; r[2] = v; r[3] = v; return r;
}
// split v = hi + lo (both bf16); residual near-exact in f32
static __device__ __forceinline__ void splitf(float v, unsigned short& h, unsigned short& l) {
    h = f2bf_bits(v);
    l = f2bf_bits(v - bf2f(h));
}
static __device__ __forceinline__ void load8split(const float* p, bf16x8& hi, bf16x8& lo) {
    const float4 a = ((const float4*)p)[0];
    const float4 b = ((const float4*)p)[1];
    const float vs[8] = {a.x, a.y, a.z, a.w, b.x, b.y, b.z, b.w};
    u16x8 uh, ul;
#pragma unroll
    for (int i = 0; i < 8; ++i) {
        unsigned short hh, ll;
        splitf(vs[i], hh, ll);
        uh[i] = hh; ul[i] = ll;
    }
    hi = __builtin_bit_cast(bf16x8, uh);
    lo = __builtin_bit_cast(bf16x8, ul);
}
static __device__ __forceinline__ bf16x8 load8bf(const float* p) {
    const float4 a = ((const float4*)p)[0];
    const float4 b = ((const float4*)p)[1];
    u16x8 u;
    u[0] = f2bf_bits(a.x); u[1] = f2bf_bits(a.y); u[2] = f2bf_bits(a.z); u[3] = f2bf_bits(a.w);
    u[4] = f2bf_bits(b.x); u[5] = f2bf_bits(b.y); u[6] = f2bf_bits(b.z); u[7] = f2bf_bits(b.w);
    return __builtin_bit_cast(bf16x8, u);
}
static __device__ __forceinline__ f32x4 mfma16(bf16x8 a, bf16x8 b, f32x4 c) {
    return __builtin_amdgcn_mfma_f32_16x16x32_bf16(a, b, c, 0, 0, 0);
}
static __device__ __forceinline__ float sigm(float x) {
    return __builtin_amdgcn_rcpf(1.0f + __expf(-x));
}
static __device__ __forceinline__ float tanh_(float x) {
    return 2.0f * __builtin_amdgcn_rcpf(1.0f + __expf(-2.0f * x)) - 1.0f;
}

// ---------------------------------------------------------------------------
// C[row,col] = A[row,:] @ W[r][col,:]^T (+bias[r][col]), split-bf16 (fp32-acc)
// MODE 0: f32 out [row*OUTC+col]                 (tc = conn @ trans.T)
// MODE 2: bf16 out, gate-quad packed             (xW = x @ W_ih.T + b_lstm)
// quad offset = (r*NN+row)*512 + (col&127)*4 + (col>>7)
// ---------------------------------------------------------------------------
template <int OUTC, int MODE>
__global__ __launch_bounds__(512, 2) void gemm_rt(
    const float* __restrict__ A, const float* __restrict__ W,
    const float* __restrict__ bias, void* __restrict__ outp)
{
    constexpr int CW = OUTC / 8;
    constexpr int CT = CW / 16;
    const int tid = threadIdx.x;
    const int w = tid >> 6, lane = tid & 63;
    const int g = lane >> 4, m = lane & 15;
    const int n0 = blockIdx.x * 64;
    const int r = blockIdx.y;
    const float* Wr = W + (size_t)r * OUTC * HD;

    f32x4 acc[4][CT];
#pragma unroll
    for (int rt = 0; rt < 4; ++rt)
#pragma unroll
        for (int ct = 0; ct < CT; ++ct) acc[rt][ct] = f4splat(0.0f);

#pragma unroll
    for (int kc = 0; kc < 4; ++kc) {
        bf16x8 ah[4], al[4];
#pragma unroll
        for (int rt = 0; rt < 4; ++rt)
            load8split(A + (size_t)(n0 + rt * 16 + m) * HD + kc * 32 + 8 * g, ah[rt], al[rt]);
        bf16x8 bh[CT], bl[CT];
#pragma unroll
        for (int ct = 0; ct < CT; ++ct)
            load8split(Wr + (size_t)(w * CW + ct * 16 + m) * HD + kc * 32 + 8 * g, bh[ct], bl[ct]);
#pragma unroll
        for (int rt = 0; rt < 4; ++rt)
#pragma unroll
            for (int ct = 0; ct < CT; ++ct) {
                acc[rt][ct] = mfma16(ah[rt], bh[ct], acc[rt][ct]);
                acc[rt][ct] = mfma16(al[rt], bh[ct], acc[rt][ct]);
                acc[rt][ct] = mfma16(ah[rt], bl[ct], acc[rt][ct]);
            }
    }

#pragma unroll
    for (int rt = 0; rt < 4; ++rt)
#pragma unroll
        for (int ct = 0; ct < CT; ++ct) {
            const int col = w * CW + ct * 16 + m;
            const float bv = bias ? bias[r * OUTC + col] : 0.0f;
#pragma unroll
            for (int e = 0; e < 4; ++e) {
                const int row = n0 + rt * 16 + 4 * g + e;
                const float v = acc[rt][ct][e] + bv;
                if constexpr (MODE == 0) {
                    ((float*)outp)[(size_t)row * OUTC + col] = v;
                } else {
                    ((unsigned short*)outp)[((size_t)r * NN + row) * G4 + (size_t)(col & 127) * 4 + (col >> 7)] =
                        f2bf_bits(v);
                }
            }
        }
}

// ---------------------------------------------------------------------------
// One relation per block (blockIdx.y = r), 64 nodes/block.
// h: bf16 hi+lo, double-buffered in LDS (1 barrier/step), XOR-swizzled.
// xW gather: bf16 gate-quads, cross-step prefetched into registers.
// ---------------------------------------------------------------------------
__global__ __launch_bounds__(512, 2) void lstm_kernel(
    const float* __restrict__ x, const int* __restrict__ nbr,
    const float* __restrict__ Whh, const float* __restrict__ fcs,
    const float* __restrict__ fcn, const float* __restrict__ bias,
    const unsigned short* __restrict__ xW, float* __restrict__ Xout)
{
    __shared__ unsigned short h_hi[2][64 * HD];   // [buf][row*HD + (col^((row&7)<<3))]
    __shared__ unsigned short h_lo[2][64 * HD];
    __shared__ int idx_lds[64 * KST];

    const int tid = threadIdx.x;
    const int w = tid >> 6, lane = tid & 63;
    const int g = lane >> 4, m = lane & 15;
    const int n0 = blockIdx.x * 64;
    const int r = blockIdx.y;

    for (int i = tid; i < 64 * KST; i += 512)
        idx_lds[i] = nbr[((size_t)r * NN + n0 + (i >> 4)) * KST + (i & 15)];

    // Whh B-fragments: wave w owns gate cols q*128 + w*16 + m, resident in regs
    bf16x8 bw[4][4];
    const float* whr = Whh + (size_t)r * G4 * HD;
#pragma unroll
    for (int q = 0; q < 4; ++q)
#pragma unroll
        for (int kc = 0; kc < 4; ++kc)
            bw[q][kc] = load8bf(whr + (size_t)(q * 128 + w * 16 + m) * HD + kc * 32 + 8 * g);

    float cst[4][4];
#pragma unroll
    for (int rt = 0; rt < 4; ++rt)
#pragma unroll
        for (int e = 0; e < 4; ++e) cst[rt][e] = 0.0f;

    const unsigned short* xwr = xW + (size_t)r * NN * G4;
    __syncthreads();   // idx_lds ready

    // prefetch step 0 gather
    ushort4 xv[4][4];
#pragma unroll
    for (int rt = 0; rt < 4; ++rt)
#pragma unroll
        for (int e = 0; e < 4; ++e) {
            const int nidx = idx_lds[(rt * 16 + 4 * g + e) * KST + 0];
            xv[rt][e] = *(const ushort4*)(xwr + (size_t)nidx * G4 + (size_t)(w * 16 + m) * 4);
        }

    int cur = 0;
    for (int t = 0; t < KST; ++t) {
        // consume prefetched quads into accumulators (frees xv regs)
        f32x4 acc[4][4];
#pragma unroll
        for (int rt = 0; rt < 4; ++rt)
#pragma unroll
            for (int e = 0; e < 4; ++e) {
                acc[rt][0][e] = bf2f(xv[rt][e].x);
                acc[rt][1][e] = bf2f(xv[rt][e].y);
                acc[rt][2][e] = bf2f(xv[rt][e].z);
                acc[rt][3][e] = bf2f(xv[rt][e].w);
            }

        // prefetch next step's gather (hides L2/L3 latency under MFMA+VALU)
        if (t + 1 < KST) {
#pragma unroll
            for (int rt = 0; rt < 4; ++rt)
#pragma unroll
                for (int e = 0; e < 4; ++e) {
                    const int nidx = idx_lds[(rt * 16 + 4 * g + e) * KST + (t + 1)];
                    xv[rt][e] = *(const ushort4*)(xwr + (size_t)nidx * G4 + (size_t)(w * 16 + m) * 4);
                }
        }

        if (t > 0) {
            const unsigned short* hh = h_hi[cur];
            const unsigned short* hl = h_lo[cur];
#pragma unroll
            for (int kc = 0; kc < 4; ++kc) {
                bf16x8 a_hi[4], a_lo[4];
#pragma unroll
                for (int rt = 0; rt < 4; ++rt) {
                    const int row = rt * 16 + m;
                    const int off = row * HD + ((kc * 32 + 8 * g) ^ ((row & 7) << 3));
                    a_hi[rt] = *(const bf16x8*)&hh[off];
                    a_lo[rt] = *(const bf16x8*)&hl[off];
                }
#pragma unroll
                for (int rt = 0; rt < 4; ++rt)
#pragma unroll
                    for (int q = 0; q < 4; ++q) {
                        acc[rt][q] = mfma16(a_hi[rt], bw[q][kc], acc[rt][q]);
                        acc[rt][q] = mfma16(a_lo[rt], bw[q][kc], acc[rt][q]);
                    }
            }
        }

        // elementwise LSTM cell (gate order i,f,g,o); write h into other buffer
        unsigned short* nh = h_hi[cur ^ 1];
        unsigned short* nl = h_lo[cur ^ 1];
#pragma unroll
        for (int rt = 0; rt < 4; ++rt)
#pragma unroll
            for (int e = 0; e < 4; ++e) {
                const float iv = sigm(acc[rt][0][e]);
                const float fv = sigm(acc[rt][1][e]);
                const float gv = tanh_(acc[rt][2][e]);
                const float ov = sigm(acc[rt][3][e]);
                const float cn = fv * cst[rt][e] + iv * gv;
                cst[rt][e] = cn;
                const float hf = ov * tanh_(cn);
                unsigned short hh, ll;
                splitf(hf, hh, ll);
                const int row = rt * 16 + 4 * g + e;
                const int col = w * 16 + m;
                const int off = row * HD + (col ^ ((row & 7) << 3));
                nh[off] = hh;
                nl[off] = ll;
            }
        __syncthreads();   // h[cur^1] complete; also protects next write of h[cur]
        cur ^= 1;
    }

    // ---- FC + leaky-relu: wave w -> row tile (w&3), col half (w>>2); split-bf16
    {
        const int rt = w & 3;
        const int cth = (w >> 2) * 64;
        const float* fsr = fcs + (size_t)r * HD * HD;
        const float* fnr = fcn + (size_t)r * HD * HD;
        const unsigned short* hh_ = h_hi[cur];
        const unsigned short* hl_ = h_lo[cur];
        f32x4 oacc[4];
#pragma unroll
        for (int i = 0; i < 4; ++i)
            oacc[i] = f4splat(bias[r * HD + cth + i * 16 + m]);
#pragma unroll
        for (int kc = 0; kc < 4; ++kc) {
            const int row = rt * 16 + m;
            bf16x8 ax_hi, ax_lo;
            load8split(x + (size_t)(n0 + row) * HD + kc * 32 + 8 * g, ax_hi, ax_lo);
            const int off = row * HD + ((kc * 32 + 8 * g) ^ ((row & 7) << 3));
            const bf16x8 ah_hi = *(const bf16x8*)&hh_[off];
            const bf16x8 ah_lo = *(const bf16x8*)&hl_[off];
#pragma unroll
            for (int i = 0; i < 4; ++i) {
                bf16x8 bs_hi, bs_lo, bn_hi, bn_lo;
                load8split(fsr + (size_t)(cth + i * 16 + m) * HD + kc * 32 + 8 * g, bs_hi, bs_lo);
                load8split(fnr + (size_t)(cth + i * 16 + m) * HD + kc * 32 + 8 * g, bn_hi, bn_lo);
                oacc[i] = mfma16(ax_hi, bs_hi, oacc[i]);
                oacc[i] = mfma16(ax_lo, bs_hi, oacc[i]);
                oacc[i] = mfma16(ax_hi, bs_lo, oacc[i]);
                oacc[i] = mfma16(ah_hi, bn_hi, oacc[i]);
                oacc[i] = mfma16(ah_lo, bn_hi, oacc[i]);
                oacc[i] = mfma16(ah_hi, bn_lo, oacc[i]);
            }
        }
#pragma unroll
        for (int i = 0; i < 4; ++i)
#pragma unroll
            for (int e = 0; e < 4; ++e) {
                const int row = rt * 16 + 4 * g + e;
                const int col = cth + i * 16 + m;
                float v = oacc[i][e];
                v = v > 0.0f ? v : 0.01f * v;
                Xout[((size_t)(n0 + row) * NRELS + r) * HD + col] = v;
            }
    }
}

// ---------------------------------------------------------------------------
// attention: one wave per node; softmax over 3 relations, f32 throughout
// ---------------------------------------------------------------------------
__global__ __launch_bounds__(256) void attn_kernel(
    const float* __restrict__ X, const float* __restrict__ tc,
    float* __restrict__ out)
{
    const int wv = blockIdx.x * (blockDim.x >> 6) + (threadIdx.x >> 6);
    const int lane = threadIdx.x & 63;
    if (wv >= NN) return;
    const size_t nb = (size_t)wv;

    const float t0 = tc[nb * HD + lane];
    const float t1 = tc[nb * HD + 64 + lane];
    float x0[3], x1[3], sc[3];
#pragma unroll
    for (int r = 0; r < 3; ++r) {
        x0[r] = X[(nb * 3 + r) * HD + lane];
        x1[r] = X[(nb * 3 + r) * HD + 64 + lane];
        float p = x0[r] * t0 + x1[r] * t1;
#pragma unroll
        for (int off = 32; off >= 1; off >>= 1)
            p += __shfl_xor(p, off, 64);
        sc[r] = p;
    }
    const float mx = fmaxf(sc[0], fmaxf(sc[1], sc[2]));
    const float e0 = __expf(sc[0] - mx), e1 = __expf(sc[1] - mx), e2 = __expf(sc[2] - mx);
    const float inv = __builtin_amdgcn_rcpf(e0 + e1 + e2);
    const float a0 = e0 * inv, a1 = e1 * inv, a2 = e2 * inv;
    out[nb * HD + lane]      = a0 * x0[0] + a1 * x0[1] + a2 * x0[2];
    out[nb * HD + 64 + lane] = a0 * x1[0] + a1 * x1[1] + a2 * x1[2];
}

extern "C" void kernel_launch(void* const* d_in, const int* in_sizes, int n_in,
                              void* d_out, int out_size, void* d_ws, size_t ws_size,
                              hipStream_t stream)
{
    const float* x     = (const float*)d_in[0];
    const float* conn  = (const float*)d_in[1];
    const int*   nbr   = (const int*)d_in[2];
    const float* trans = (const float*)d_in[3];
    const float* Wih   = (const float*)d_in[4];
    const float* Whh   = (const float*)d_in[5];
    const float* blstm = (const float*)d_in[6];
    const float* fcs   = (const float*)d_in[7];
    const float* fcn   = (const float*)d_in[8];
    const float* bias  = (const float*)d_in[9];
    float* out = (float*)d_out;

    // ws carve: xW bf16 [3][N][512] | tc f32 [N][128] | X f32 [N][3][128]
    const size_t XW_B = (size_t)NRELS * NN * G4 * 2;   //  50.3 MB
    const size_t TC_B = (size_t)NN * HD * 4;           //   8.4 MB
    const size_t XO_B = (size_t)NN * NRELS * HD * 4;   //  25.2 MB
    if (ws_size < XW_B + TC_B + XO_B) return;          //  83.9 MB floor

    char* wsb = (char*)d_ws;
    unsigned short* xW = (unsigned short*)wsb;
    float*          tc = (float*)(wsb + XW_B);
    float*          Xo = (float*)(wsb + XW_B + TC_B);

    gemm_rt<512, 2><<<dim3(NN / 64, NRELS), 512, 0, stream>>>(x, Wih, blstm, (void*)xW);
    gemm_rt<128, 0><<<dim3(NN / 64, 1), 512, 0, stream>>>(conn, trans, nullptr, (void*)tc);
    lstm_kernel<<<dim3(NN / 64, NRELS), 512, 0, stream>>>(x, nbr, Whh, fcs, fcn, bias, xW, Xo);
    attn_kernel<<<dim3(NN / 4), 256, 0, stream>>>(Xo, tc, out);
}

// Round 4
// 349.381 us; speedup vs baseline: 1.2531x; 1.1599x over previous
//
#include <hip/hip_runtime.h>

#define NN    16384
#define HD    128
#define G4    512
#define KST   16
#define NRELS 3

using f16x8 = __attribute__((ext_vector_type(8))) _Float16;
using f32x4 = __attribute__((ext_vector_type(4))) float;

static __device__ __forceinline__ f32x4 f4splat(float v) {
    f32x4 r; r[0] = v; r[1] = v; r[2] = v; r[3] = v; return r;
}
static __device__ __forceinline__ f16x8 load8h(const float* p) {
    const float4 a = ((const float4*)p)[0];
    const float4 b = ((const float4*)p)[1];
    f16x8 r;
    r[0] = (_Float16)a.x; r[1] = (_Float16)a.y; r[2] = (_Float16)a.z; r[3] = (_Float16)a.w;
    r[4] = (_Float16)b.x; r[5] = (_Float16)b.y; r[6] = (_Float16)b.z; r[7] = (_Float16)b.w;
    return r;
}
static __device__ __forceinline__ f32x4 mfma16h(f16x8 a, f16x8 b, f32x4 c) {
    return __builtin_amdgcn_mfma_f32_16x16x32_f16(a, b, c, 0, 0, 0);
}
static __device__ __forceinline__ unsigned short f2h_bits(float f) {
    return __builtin_bit_cast(unsigned short, (_Float16)f);
}
static __device__ __forceinline__ float h2f(unsigned short b) {
    return (float)__builtin_bit_cast(_Float16, b);
}
static __device__ __forceinline__ float sigm(float x) {
    return __builtin_amdgcn_rcpf(1.0f + __expf(-x));
}
static __device__ __forceinline__ float tanh_(float x) {
    return 2.0f * __builtin_amdgcn_rcpf(1.0f + __expf(-2.0f * x)) - 1.0f;
}

// ---------------------------------------------------------------------------
// C[row,col] = A[row,:] @ W[r][col,:]^T (+bias[r][col]); fp16 inputs, f32 acc.
// MODE 0: f32 out [row*OUTC+col]            (tc = conn @ trans.T)
// MODE 1: fp16-bits out, gate-quad packed   (xW = x @ W_ih.T + b_lstm)
//         quad offset = (r*NN+row)*512 + (col&127)*4 + (col>>7)
// ---------------------------------------------------------------------------
template <int OUTC, int MODE>
__global__ __launch_bounds__(512, 2) void gemm_rt(
    const float* __restrict__ A, const float* __restrict__ W,
    const float* __restrict__ bias, void* __restrict__ outp)
{
    constexpr int CW = OUTC / 8;
    constexpr int CT = CW / 16;
    const int tid = threadIdx.x;
    const int w = tid >> 6, lane = tid & 63;
    const int g = lane >> 4, m = lane & 15;
    const int n0 = blockIdx.x * 64;
    const int r = blockIdx.y;
    const float* Wr = W + (size_t)r * OUTC * HD;

    f32x4 acc[4][CT];
#pragma unroll
    for (int rt = 0; rt < 4; ++rt)
#pragma unroll
        for (int ct = 0; ct < CT; ++ct) acc[rt][ct] = f4splat(0.0f);

#pragma unroll
    for (int kc = 0; kc < 4; ++kc) {
        f16x8 a[4];
#pragma unroll
        for (int rt = 0; rt < 4; ++rt)
            a[rt] = load8h(A + (size_t)(n0 + rt * 16 + m) * HD + kc * 32 + 8 * g);
        f16x8 b[CT];
#pragma unroll
        for (int ct = 0; ct < CT; ++ct)
            b[ct] = load8h(Wr + (size_t)(w * CW + ct * 16 + m) * HD + kc * 32 + 8 * g);
#pragma unroll
        for (int rt = 0; rt < 4; ++rt)
#pragma unroll
            for (int ct = 0; ct < CT; ++ct)
                acc[rt][ct] = mfma16h(a[rt], b[ct], acc[rt][ct]);
    }

#pragma unroll
    for (int rt = 0; rt < 4; ++rt)
#pragma unroll
        for (int ct = 0; ct < CT; ++ct) {
            const int col = w * CW + ct * 16 + m;
            const float bv = bias ? bias[r * OUTC + col] : 0.0f;
#pragma unroll
            for (int e = 0; e < 4; ++e) {
                const int row = n0 + rt * 16 + 4 * g + e;
                const float v = acc[rt][ct][e] + bv;
                if constexpr (MODE == 0) {
                    ((float*)outp)[(size_t)row * OUTC + col] = v;
                } else {
                    ((unsigned short*)outp)[((size_t)r * NN + row) * G4 + (size_t)(col & 127) * 4 + (col >> 7)] =
                        f2h_bits(v);
                }
            }
        }
}

// ---------------------------------------------------------------------------
// One relation per block (blockIdx.y = r), 64 nodes/block.
// h: fp16, double-buffered in LDS (1 barrier/step), XOR-swizzled.
// xW gather: fp16 gate-quads (8 B/lane), cross-step prefetched into registers.
// Whh fp16 B-fragments resident in registers (wave w owns gate cols q*128+w*16+m).
// ---------------------------------------------------------------------------
__global__ __launch_bounds__(512, 2) void lstm_kernel(
    const float* __restrict__ x, const int* __restrict__ nbr,
    const float* __restrict__ Whh, const float* __restrict__ fcs,
    const float* __restrict__ fcn, const float* __restrict__ bias,
    const unsigned short* __restrict__ xW, float* __restrict__ Xout)
{
    __shared__ unsigned short h_lds[2][64 * HD];   // fp16 bits, [buf][row*HD + (col^((row&7)<<3))]
    __shared__ int idx_lds[64 * KST];

    const int tid = threadIdx.x;
    const int w = tid >> 6, lane = tid & 63;
    const int g = lane >> 4, m = lane & 15;
    const int n0 = blockIdx.x * 64;
    const int r = blockIdx.y;

    for (int i = tid; i < 64 * KST; i += 512)
        idx_lds[i] = nbr[((size_t)r * NN + n0 + (i >> 4)) * KST + (i & 15)];

    // Whh B-fragments, resident for all 16 steps
    f16x8 bw[4][4];
    const float* whr = Whh + (size_t)r * G4 * HD;
#pragma unroll
    for (int q = 0; q < 4; ++q)
#pragma unroll
        for (int kc = 0; kc < 4; ++kc)
            bw[q][kc] = load8h(whr + (size_t)(q * 128 + w * 16 + m) * HD + kc * 32 + 8 * g);

    float cst[4][4];
#pragma unroll
    for (int rt = 0; rt < 4; ++rt)
#pragma unroll
        for (int e = 0; e < 4; ++e) cst[rt][e] = 0.0f;

    const unsigned short* xwr = xW + (size_t)r * NN * G4;
    __syncthreads();   // idx_lds ready

    // prefetch step 0 gather (quad = 4 fp16 gate pre-activations, 8 B)
    ushort4 xv[4][4];
#pragma unroll
    for (int rt = 0; rt < 4; ++rt)
#pragma unroll
        for (int e = 0; e < 4; ++e) {
            const int nidx = idx_lds[(rt * 16 + 4 * g + e) * KST + 0];
            xv[rt][e] = *(const ushort4*)(xwr + (size_t)nidx * G4 + (size_t)(w * 16 + m) * 4);
        }

    int cur = 0;
    for (int t = 0; t < KST; ++t) {
        // consume prefetched quads into accumulators
        f32x4 acc[4][4];
#pragma unroll
        for (int rt = 0; rt < 4; ++rt)
#pragma unroll
            for (int e = 0; e < 4; ++e) {
                acc[rt][0][e] = h2f(xv[rt][e].x);
                acc[rt][1][e] = h2f(xv[rt][e].y);
                acc[rt][2][e] = h2f(xv[rt][e].z);
                acc[rt][3][e] = h2f(xv[rt][e].w);
            }

        // prefetch next step's gather (hides cache latency under MFMA+VALU)
        if (t + 1 < KST) {
#pragma unroll
            for (int rt = 0; rt < 4; ++rt)
#pragma unroll
                for (int e = 0; e < 4; ++e) {
                    const int nidx = idx_lds[(rt * 16 + 4 * g + e) * KST + (t + 1)];
                    xv[rt][e] = *(const ushort4*)(xwr + (size_t)nidx * G4 + (size_t)(w * 16 + m) * 4);
                }
        }

        if (t > 0) {
            const unsigned short* hb = h_lds[cur];
#pragma unroll
            for (int kc = 0; kc < 4; ++kc) {
                f16x8 a[4];
#pragma unroll
                for (int rt = 0; rt < 4; ++rt) {
                    const int row = rt * 16 + m;
                    a[rt] = *(const f16x8*)&hb[row * HD + ((kc * 32 + 8 * g) ^ ((row & 7) << 3))];
                }
#pragma unroll
                for (int rt = 0; rt < 4; ++rt)
#pragma unroll
                    for (int q = 0; q < 4; ++q)
                        acc[rt][q] = mfma16h(a[rt], bw[q][kc], acc[rt][q]);
            }
        }

        // elementwise LSTM cell (gate order i,f,g,o); h -> other buffer
        unsigned short* nh = h_lds[cur ^ 1];
#pragma unroll
        for (int rt = 0; rt < 4; ++rt)
#pragma unroll
            for (int e = 0; e < 4; ++e) {
                const float iv = sigm(acc[rt][0][e]);
                const float fv = sigm(acc[rt][1][e]);
                const float gv = tanh_(acc[rt][2][e]);
                const float ov = sigm(acc[rt][3][e]);
                const float cn = fv * cst[rt][e] + iv * gv;
                cst[rt][e] = cn;
                const float hf = ov * tanh_(cn);
                const int row = rt * 16 + 4 * g + e;
                const int col = w * 16 + m;
                nh[row * HD + (col ^ ((row & 7) << 3))] = f2h_bits(hf);
            }
        __syncthreads();   // h[cur^1] complete; protects next overwrite of h[cur]
        cur ^= 1;
    }

    // ---- FC + leaky-relu: wave w -> row tile (w&3), col half (w>>2); fp16
    {
        const int rt = w & 3;
        const int cth = (w >> 2) * 64;
        const float* fsr = fcs + (size_t)r * HD * HD;
        const float* fnr = fcn + (size_t)r * HD * HD;
        const unsigned short* hb = h_lds[cur];
        f32x4 oacc[4];
#pragma unroll
        for (int i = 0; i < 4; ++i)
            oacc[i] = f4splat(bias[r * HD + cth + i * 16 + m]);
#pragma unroll
        for (int kc = 0; kc < 4; ++kc) {
            const int row = rt * 16 + m;
            const f16x8 ax = load8h(x + (size_t)(n0 + row) * HD + kc * 32 + 8 * g);
            const f16x8 ah = *(const f16x8*)&hb[row * HD + ((kc * 32 + 8 * g) ^ ((row & 7) << 3))];
#pragma unroll
            for (int i = 0; i < 4; ++i) {
                const f16x8 bs = load8h(fsr + (size_t)(cth + i * 16 + m) * HD + kc * 32 + 8 * g);
                const f16x8 bn = load8h(fnr + (size_t)(cth + i * 16 + m) * HD + kc * 32 + 8 * g);
                oacc[i] = mfma16h(ax, bs, oacc[i]);
                oacc[i] = mfma16h(ah, bn, oacc[i]);
            }
        }
#pragma unroll
        for (int i = 0; i < 4; ++i)
#pragma unroll
            for (int e = 0; e < 4; ++e) {
                const int row = rt * 16 + 4 * g + e;
                const int col = cth + i * 16 + m;
                float v = oacc[i][e];
                v = v > 0.0f ? v : 0.01f * v;
                Xout[((size_t)(n0 + row) * NRELS + r) * HD + col] = v;
            }
    }
}

// ---------------------------------------------------------------------------
// attention: one wave per node; softmax over 3 relations, f32 throughout
// ---------------------------------------------------------------------------
__global__ __launch_bounds__(256) void attn_kernel(
    const float* __restrict__ X, const float* __restrict__ tc,
    float* __restrict__ out)
{
    const int wv = blockIdx.x * (blockDim.x >> 6) + (threadIdx.x >> 6);
    const int lane = threadIdx.x & 63;
    if (wv >= NN) return;
    const size_t nb = (size_t)wv;

    const float t0 = tc[nb * HD + lane];
    const float t1 = tc[nb * HD + 64 + lane];
    float x0[3], x1[3], sc[3];
#pragma unroll
    for (int r = 0; r < 3; ++r) {
        x0[r] = X[(nb * 3 + r) * HD + lane];
        x1[r] = X[(nb * 3 + r) * HD + 64 + lane];
        float p = x0[r] * t0 + x1[r] * t1;
#pragma unroll
        for (int off = 32; off >= 1; off >>= 1)
            p += __shfl_xor(p, off, 64);
        sc[r] = p;
    }
    const float mx = fmaxf(sc[0], fmaxf(sc[1], sc[2]));
    const float e0 = __expf(sc[0] - mx), e1 = __expf(sc[1] - mx), e2 = __expf(sc[2] - mx);
    const float inv = __builtin_amdgcn_rcpf(e0 + e1 + e2);
    const float a0 = e0 * inv, a1 = e1 * inv, a2 = e2 * inv;
    out[nb * HD + lane]      = a0 * x0[0] + a1 * x0[1] + a2 * x0[2];
    out[nb * HD + 64 + lane] = a0 * x1[0] + a1 * x1[1] + a2 * x1[2];
}

extern "C" void kernel_launch(void* const* d_in, const int* in_sizes, int n_in,
                              void* d_out, int out_size, void* d_ws, size_t ws_size,
                              hipStream_t stream)
{
    const float* x     = (const float*)d_in[0];
    const float* conn  = (const float*)d_in[1];
    const int*   nbr   = (const int*)d_in[2];
    const float* trans = (const float*)d_in[3];
    const float* Wih   = (const float*)d_in[4];
    const float* Whh   = (const float*)d_in[5];
    const float* blstm = (const float*)d_in[6];
    const float* fcs   = (const float*)d_in[7];
    const float* fcn   = (const float*)d_in[8];
    const float* bias  = (const float*)d_in[9];
    float* out = (float*)d_out;

    // ws carve: xW fp16 [3][N][512] | tc f32 [N][128] | X f32 [N][3][128]
    const size_t XW_B = (size_t)NRELS * NN * G4 * 2;   //  50.3 MB
    const size_t TC_B = (size_t)NN * HD * 4;           //   8.4 MB
    const size_t XO_B = (size_t)NN * NRELS * HD * 4;   //  25.2 MB
    if (ws_size < XW_B + TC_B + XO_B) return;          //  83.9 MB floor

    char* wsb = (char*)d_ws;
    unsigned short* xW = (unsigned short*)wsb;
    float*          tc = (float*)(wsb + XW_B);
    float*          Xo = (float*)(wsb + XW_B + TC_B);

    gemm_rt<512, 1><<<dim3(NN / 64, NRELS), 512, 0, stream>>>(x, Wih, blstm, (void*)xW);
    gemm_rt<128, 0><<<dim3(NN / 64, 1), 512, 0, stream>>>(conn, trans, nullptr, (void*)tc);
    lstm_kernel<<<dim3(NN / 64, NRELS), 512, 0, stream>>>(x, nbr, Whh, fcs, fcn, bias, xW, Xo);
    attn_kernel<<<dim3(NN / 4), 256, 0, stream>>>(Xo, tc, out);
}

// Round 5
// 335.245 us; speedup vs baseline: 1.3059x; 1.0422x over previous
//
#include <hip/hip_runtime.h>

#define NN    16384
#define HD    128
#define G4    512
#define KST   16
#define NRELS 3

using f16x8 = __attribute__((ext_vector_type(8))) _Float16;
using f32x4 = __attribute__((ext_vector_type(4))) float;

static __device__ __forceinline__ f32x4 f4splat(float v) {
    f32x4 r; r[0] = v; r[1] = v; r[2] = v; r[3] = v; return r;
}
static __device__ __forceinline__ f16x8 load8h(const float* p) {
    const float4 a = ((const float4*)p)[0];
    const float4 b = ((const float4*)p)[1];
    f16x8 r;
    r[0] = (_Float16)a.x; r[1] = (_Float16)a.y; r[2] = (_Float16)a.z; r[3] = (_Float16)a.w;
    r[4] = (_Float16)b.x; r[5] = (_Float16)b.y; r[6] = (_Float16)b.z; r[7] = (_Float16)b.w;
    return r;
}
static __device__ __forceinline__ f32x4 mfma16h(f16x8 a, f16x8 b, f32x4 c) {
    return __builtin_amdgcn_mfma_f32_16x16x32_f16(a, b, c, 0, 0, 0);
}
static __device__ __forceinline__ unsigned short f2h_bits(float f) {
    return __builtin_bit_cast(unsigned short, (_Float16)f);
}
static __device__ __forceinline__ float h2f(unsigned short b) {
    return (float)__builtin_bit_cast(_Float16, b);
}
static __device__ __forceinline__ float sigm(float x) {
    return __builtin_amdgcn_rcpf(1.0f + __expf(-x));
}
static __device__ __forceinline__ float tanh_(float x) {
    return 2.0f * __builtin_amdgcn_rcpf(1.0f + __expf(-2.0f * x)) - 1.0f;
}

// ---------------------------------------------------------------------------
// C[row,col] = A[row,:] @ W[r][col,:]^T (+bias[r][col]); fp16 inputs, f32 acc.
// MODE 0: f32 out [row*OUTC+col]            (tc = conn @ trans.T)
// MODE 1: fp16-bits out, gate-quad packed   (xW = x @ W_ih.T + b_lstm)
//         quad offset = (r*NN+row)*512 + (col&127)*4 + (col>>7)
// ---------------------------------------------------------------------------
template <int OUTC, int MODE>
__global__ __launch_bounds__(512, 2) void gemm_rt(
    const float* __restrict__ A, const float* __restrict__ W,
    const float* __restrict__ bias, void* __restrict__ outp)
{
    constexpr int CW = OUTC / 8;
    constexpr int CT = CW / 16;
    const int tid = threadIdx.x;
    const int w = tid >> 6, lane = tid & 63;
    const int g = lane >> 4, m = lane & 15;
    const int n0 = blockIdx.x * 64;
    const int r = blockIdx.y;
    const float* Wr = W + (size_t)r * OUTC * HD;

    f32x4 acc[4][CT];
#pragma unroll
    for (int rt = 0; rt < 4; ++rt)
#pragma unroll
        for (int ct = 0; ct < CT; ++ct) acc[rt][ct] = f4splat(0.0f);

#pragma unroll
    for (int kc = 0; kc < 4; ++kc) {
        f16x8 a[4];
#pragma unroll
        for (int rt = 0; rt < 4; ++rt)
            a[rt] = load8h(A + (size_t)(n0 + rt * 16 + m) * HD + kc * 32 + 8 * g);
        f16x8 b[CT];
#pragma unroll
        for (int ct = 0; ct < CT; ++ct)
            b[ct] = load8h(Wr + (size_t)(w * CW + ct * 16 + m) * HD + kc * 32 + 8 * g);
#pragma unroll
        for (int rt = 0; rt < 4; ++rt)
#pragma unroll
            for (int ct = 0; ct < CT; ++ct)
                acc[rt][ct] = mfma16h(a[rt], b[ct], acc[rt][ct]);
    }

#pragma unroll
    for (int rt = 0; rt < 4; ++rt)
#pragma unroll
        for (int ct = 0; ct < CT; ++ct) {
            const int col = w * CW + ct * 16 + m;
            const float bv = bias ? bias[r * OUTC + col] : 0.0f;
#pragma unroll
            for (int e = 0; e < 4; ++e) {
                const int row = n0 + rt * 16 + 4 * g + e;
                const float v = acc[rt][ct][e] + bv;
                if constexpr (MODE == 0) {
                    ((float*)outp)[(size_t)row * OUTC + col] = v;
                } else {
                    ((unsigned short*)outp)[((size_t)r * NN + row) * G4 + (size_t)(col & 127) * 4 + (col >> 7)] =
                        f2h_bits(v);
                }
            }
        }
}

// ---- lstm helper ops (all force-inlined; operate on one 32-node tile) ------
static __device__ __forceinline__ void consume_xw(f32x4 (&acc)[2][4], const ushort4 (&xv)[2][4]) {
#pragma unroll
    for (int rt = 0; rt < 2; ++rt)
#pragma unroll
        for (int e = 0; e < 4; ++e) {
            acc[rt][0][e] = h2f(xv[rt][e].x);
            acc[rt][1][e] = h2f(xv[rt][e].y);
            acc[rt][2][e] = h2f(xv[rt][e].z);
            acc[rt][3][e] = h2f(xv[rt][e].w);
        }
}
// idxt: per-tile idx table [32][KST], entries pre-shifted (<<10 = byte offset)
static __device__ __forceinline__ void prefetch_xw(ushort4 (&xv)[2][4], const int* idxt, int t,
                                                   const char* xwr, int laneoff, int g) {
#pragma unroll
    for (int rt = 0; rt < 2; ++rt)
#pragma unroll
        for (int e = 0; e < 4; ++e) {
            const unsigned off = (unsigned)idxt[(rt * 16 + 4 * g + e) * KST + t] + laneoff;
            xv[rt][e] = *(const ushort4*)(xwr + off);
        }
}
static __device__ __forceinline__ void mfma_h(f32x4 (&acc)[2][4], const unsigned short* hbuf,
                                              const f16x8 (&bw)[4][4], int m, int g) {
#pragma unroll
    for (int kc = 0; kc < 4; ++kc) {
        f16x8 a[2];
#pragma unroll
        for (int rt = 0; rt < 2; ++rt) {
            const int row = rt * 16 + m;
            a[rt] = *(const f16x8*)&hbuf[row * HD + ((kc * 32 + 8 * g) ^ ((row & 7) << 3))];
        }
#pragma unroll
        for (int rt = 0; rt < 2; ++rt)
#pragma unroll
            for (int q = 0; q < 4; ++q)
                acc[rt][q] = mfma16h(a[rt], bw[q][kc], acc[rt][q]);
    }
}
static __device__ __forceinline__ void lstm_elem(const f32x4 (&acc)[2][4], float (&cst)[2][4],
                                                 unsigned short* hbuf, int g, int m, int w) {
#pragma unroll
    for (int rt = 0; rt < 2; ++rt)
#pragma unroll
        for (int e = 0; e < 4; ++e) {
            const float iv = sigm(acc[rt][0][e]);
            const float fv = sigm(acc[rt][1][e]);
            const float gv = tanh_(acc[rt][2][e]);
            const float ov = sigm(acc[rt][3][e]);
            const float cn = fv * cst[rt][e] + iv * gv;
            cst[rt][e] = cn;
            const float hf = ov * tanh_(cn);
            const int row = rt * 16 + 4 * g + e;
            const int col = w * 16 + m;
            hbuf[row * HD + (col ^ ((row & 7) << 3))] = f2h_bits(hf);
        }
}

// ---------------------------------------------------------------------------
// One relation per block (blockIdx.y = r), 64 nodes in TWO 32-node tiles (A,B)
// software-pipelined half a step apart: each phase = {MFMA+gather of one tile}
// interleaved with {elementwise of the other} -> trans/VALU and MFMA/mem pipes
// both stay busy within 2 waves/SIMD. h single-buffered per tile, XOR-swizzled.
// ---------------------------------------------------------------------------
__global__ __launch_bounds__(512, 2) void lstm_kernel(
    const float* __restrict__ x, const int* __restrict__ nbr,
    const float* __restrict__ Whh, const float* __restrict__ fcs,
    const float* __restrict__ fcn, const float* __restrict__ bias,
    const unsigned short* __restrict__ xW, float* __restrict__ Xout)
{
    __shared__ unsigned short h_A[32 * HD];   // fp16 bits, [row][col^((row&7)<<3)]
    __shared__ unsigned short h_B[32 * HD];
    __shared__ int idx_lds[64 * KST];         // pre-shifted byte offsets (idx<<10)

    const int tid = threadIdx.x;
    const int w = tid >> 6, lane = tid & 63;
    const int g = lane >> 4, m = lane & 15;
    const int n0 = blockIdx.x * 64;
    const int r = blockIdx.y;
    const int laneoff = (w * 16 + m) * 8;
    const char* xwr = (const char*)(xW + (size_t)r * NN * G4);

    for (int i = tid; i < 64 * KST; i += 512)
        idx_lds[i] = nbr[((size_t)r * NN + n0 + (i >> 4)) * KST + (i & 15)] << 10;

    // Whh B-fragments: wave w owns gate cols q*128 + w*16 + m, resident in regs
    f16x8 bw[4][4];
    const float* whr = Whh + (size_t)r * G4 * HD;
#pragma unroll
    for (int q = 0; q < 4; ++q)
#pragma unroll
        for (int kc = 0; kc < 4; ++kc)
            bw[q][kc] = load8h(whr + (size_t)(q * 128 + w * 16 + m) * HD + kc * 32 + 8 * g);

    float cst_A[2][4], cst_B[2][4];
#pragma unroll
    for (int rt = 0; rt < 2; ++rt)
#pragma unroll
        for (int e = 0; e < 4; ++e) { cst_A[rt][e] = 0.0f; cst_B[rt][e] = 0.0f; }

    __syncthreads();   // idx_lds ready

    ushort4 xv_A[2][4], xv_B[2][4];
    prefetch_xw(xv_A, idx_lds, 0, xwr, laneoff, g);
    prefetch_xw(xv_B, idx_lds + 32 * KST, 0, xwr, laneoff, g);

    f32x4 acc_A[2][4], acc_B[2][4];
    for (int k = 0; k < KST; ++k) {
        // Phase A: compute tile-A gates(k)  ||  finish tile-B step k-1
        consume_xw(acc_A, xv_A);
        if (k + 1 < KST) prefetch_xw(xv_A, idx_lds, k + 1, xwr, laneoff, g);
        if (k > 0) mfma_h(acc_A, h_A, bw, m, g);
        if (k > 0) lstm_elem(acc_B, cst_B, h_B, g, m, w);   // writes h_B(k-1)
        __syncthreads();
        // Phase B: compute tile-B gates(k)  ||  finish tile-A step k
        consume_xw(acc_B, xv_B);
        if (k + 1 < KST) prefetch_xw(xv_B, idx_lds + 32 * KST, k + 1, xwr, laneoff, g);
        if (k > 0) mfma_h(acc_B, h_B, bw, m, g);
        lstm_elem(acc_A, cst_A, h_A, g, m, w);              // writes h_A(k)
        __syncthreads();
    }
    lstm_elem(acc_B, cst_B, h_B, g, m, w);                  // h_B(KST-1)
    __syncthreads();

    // ---- FC + leaky-relu: wave w -> row tile (w&3) of 64, col half (w>>2)
    {
        const int ert = w & 3;
        const int cth = (w >> 2) * 64;
        const unsigned short* hb = (ert < 2) ? h_A : h_B;
        const int lr0 = (ert & 1) * 16;                     // tile-local row base
        const float* fsr = fcs + (size_t)r * HD * HD;
        const float* fnr = fcn + (size_t)r * HD * HD;
        f32x4 oacc[4];
#pragma unroll
        for (int i = 0; i < 4; ++i)
            oacc[i] = f4splat(bias[r * HD + cth + i * 16 + m]);
#pragma unroll
        for (int kc = 0; kc < 4; ++kc) {
            const int lrow = lr0 + m;
            const f16x8 ax = load8h(x + (size_t)(n0 + ert * 16 + m) * HD + kc * 32 + 8 * g);
            const f16x8 ah = *(const f16x8*)&hb[lrow * HD + ((kc * 32 + 8 * g) ^ ((lrow & 7) << 3))];
#pragma unroll
            for (int i = 0; i < 4; ++i) {
                const f16x8 bs = load8h(fsr + (size_t)(cth + i * 16 + m) * HD + kc * 32 + 8 * g);
                const f16x8 bn = load8h(fnr + (size_t)(cth + i * 16 + m) * HD + kc * 32 + 8 * g);
                oacc[i] = mfma16h(ax, bs, oacc[i]);
                oacc[i] = mfma16h(ah, bn, oacc[i]);
            }
        }
#pragma unroll
        for (int i = 0; i < 4; ++i)
#pragma unroll
            for (int e = 0; e < 4; ++e) {
                const int row = ert * 16 + 4 * g + e;
                const int col = cth + i * 16 + m;
                float v = oacc[i][e];
                v = v > 0.0f ? v : 0.01f * v;
                Xout[((size_t)(n0 + row) * NRELS + r) * HD + col] = v;
            }
    }
}

// ---------------------------------------------------------------------------
// attention: one wave per node; softmax over 3 relations, f32 throughout
// ---------------------------------------------------------------------------
__global__ __launch_bounds__(256) void attn_kernel(
    const float* __restrict__ X, const float* __restrict__ tc,
    float* __restrict__ out)
{
    const int wv = blockIdx.x * (blockDim.x >> 6) + (threadIdx.x >> 6);
    const int lane = threadIdx.x & 63;
    if (wv >= NN) return;
    const size_t nb = (size_t)wv;

    const float t0 = tc[nb * HD + lane];
    const float t1 = tc[nb * HD + 64 + lane];
    float x0[3], x1[3], sc[3];
#pragma unroll
    for (int r = 0; r < 3; ++r) {
        x0[r] = X[(nb * 3 + r) * HD + lane];
        x1[r] = X[(nb * 3 + r) * HD + 64 + lane];
        float p = x0[r] * t0 + x1[r] * t1;
#pragma unroll
        for (int off = 32; off >= 1; off >>= 1)
            p += __shfl_xor(p, off, 64);
        sc[r] = p;
    }
    const float mx = fmaxf(sc[0], fmaxf(sc[1], sc[2]));
    const float e0 = __expf(sc[0] - mx), e1 = __expf(sc[1] - mx), e2 = __expf(sc[2] - mx);
    const float inv = __builtin_amdgcn_rcpf(e0 + e1 + e2);
    const float a0 = e0 * inv, a1 = e1 * inv, a2 = e2 * inv;
    out[nb * HD + lane]      = a0 * x0[0] + a1 * x0[1] + a2 * x0[2];
    out[nb * HD + 64 + lane] = a0 * x1[0] + a1 * x1[1] + a2 * x1[2];
}

extern "C" void kernel_launch(void* const* d_in, const int* in_sizes, int n_in,
                              void* d_out, int out_size, void* d_ws, size_t ws_size,
                              hipStream_t stream)
{
    const float* x     = (const float*)d_in[0];
    const float* conn  = (const float*)d_in[1];
    const int*   nbr   = (const int*)d_in[2];
    const float* trans = (const float*)d_in[3];
    const float* Wih   = (const float*)d_in[4];
    const float* Whh   = (const float*)d_in[5];
    const float* blstm = (const float*)d_in[6];
    const float* fcs   = (const float*)d_in[7];
    const float* fcn   = (const float*)d_in[8];
    const float* bias  = (const float*)d_in[9];
    float* out = (float*)d_out;

    // ws carve: xW fp16 [3][N][512] | tc f32 [N][128] | X f32 [N][3][128]
    const size_t XW_B = (size_t)NRELS * NN * G4 * 2;   //  50.3 MB
    const size_t TC_B = (size_t)NN * HD * 4;           //   8.4 MB
    const size_t XO_B = (size_t)NN * NRELS * HD * 4;   //  25.2 MB
    if (ws_size < XW_B + TC_B + XO_B) return;          //  83.9 MB floor

    char* wsb = (char*)d_ws;
    unsigned short* xW = (unsigned short*)wsb;
    float*          tc = (float*)(wsb + XW_B);
    float*          Xo = (float*)(wsb + XW_B + TC_B);

    gemm_rt<512, 1><<<dim3(NN / 64, NRELS), 512, 0, stream>>>(x, Wih, blstm, (void*)xW);
    gemm_rt<128, 0><<<dim3(NN / 64, 1), 512, 0, stream>>>(conn, trans, nullptr, (void*)tc);
    lstm_kernel<<<dim3(NN / 64, NRELS), 512, 0, stream>>>(x, nbr, Whh, fcs, fcn, bias, xW, Xo);
    attn_kernel<<<dim3(NN / 4), 256, 0, stream>>>(Xo, tc, out);
}

// Round 6
// 334.412 us; speedup vs baseline: 1.3092x; 1.0025x over previous
//
#include <hip/hip_runtime.h>

#define NN    16384
#define HD    128
#define G4    512
#define KST   16
#define NRELS 3
#define NPB   16   // nodes per lstm block

using f16x8 = __attribute__((ext_vector_type(8))) _Float16;
using f32x4 = __attribute__((ext_vector_type(4))) float;

static __device__ __forceinline__ f32x4 f4splat(float v) {
    f32x4 r; r[0] = v; r[1] = v; r[2] = v; r[3] = v; return r;
}
static __device__ __forceinline__ f16x8 load8h(const float* p) {
    const float4 a = ((const float4*)p)[0];
    const float4 b = ((const float4*)p)[1];
    f16x8 r;
    r[0] = (_Float16)a.x; r[1] = (_Float16)a.y; r[2] = (_Float16)a.z; r[3] = (_Float16)a.w;
    r[4] = (_Float16)b.x; r[5] = (_Float16)b.y; r[6] = (_Float16)b.z; r[7] = (_Float16)b.w;
    return r;
}
static __device__ __forceinline__ f32x4 mfma16h(f16x8 a, f16x8 b, f32x4 c) {
    return __builtin_amdgcn_mfma_f32_16x16x32_f16(a, b, c, 0, 0, 0);
}
static __device__ __forceinline__ unsigned short f2h_bits(float f) {
    return __builtin_bit_cast(unsigned short, (_Float16)f);
}
static __device__ __forceinline__ float h2f(unsigned short b) {
    return (float)__builtin_bit_cast(_Float16, b);
}
static __device__ __forceinline__ float sigm(float x) {
    return __builtin_amdgcn_rcpf(1.0f + __expf(-x));
}
static __device__ __forceinline__ float tanh_(float x) {
    return 2.0f * __builtin_amdgcn_rcpf(1.0f + __expf(-2.0f * x)) - 1.0f;
}

// ---------------------------------------------------------------------------
// C[row,col] = A[row,:] @ W[r][col,:]^T (+bias[r][col]); fp16 inputs, f32 acc.
// MODE 0: f32 out [row*OUTC+col]            (tc = conn @ trans.T)
// MODE 1: fp16-bits out, gate-quad packed   (xW = x @ W_ih.T + b_lstm)
//         quad offset = (r*NN+row)*512 + (col&127)*4 + (col>>7)
// ---------------------------------------------------------------------------
template <int OUTC, int MODE>
__global__ __launch_bounds__(512, 2) void gemm_rt(
    const float* __restrict__ A, const float* __restrict__ W,
    const float* __restrict__ bias, void* __restrict__ outp)
{
    constexpr int CW = OUTC / 8;
    constexpr int CT = CW / 16;
    const int tid = threadIdx.x;
    const int w = tid >> 6, lane = tid & 63;
    const int g = lane >> 4, m = lane & 15;
    const int n0 = blockIdx.x * 64;
    const int r = blockIdx.y;
    const float* Wr = W + (size_t)r * OUTC * HD;

    f32x4 acc[4][CT];
#pragma unroll
    for (int rt = 0; rt < 4; ++rt)
#pragma unroll
        for (int ct = 0; ct < CT; ++ct) acc[rt][ct] = f4splat(0.0f);

#pragma unroll
    for (int kc = 0; kc < 4; ++kc) {
        f16x8 a[4];
#pragma unroll
        for (int rt = 0; rt < 4; ++rt)
            a[rt] = load8h(A + (size_t)(n0 + rt * 16 + m) * HD + kc * 32 + 8 * g);
        f16x8 b[CT];
#pragma unroll
        for (int ct = 0; ct < CT; ++ct)
            b[ct] = load8h(Wr + (size_t)(w * CW + ct * 16 + m) * HD + kc * 32 + 8 * g);
#pragma unroll
        for (int rt = 0; rt < 4; ++rt)
#pragma unroll
            for (int ct = 0; ct < CT; ++ct)
                acc[rt][ct] = mfma16h(a[rt], b[ct], acc[rt][ct]);
    }

#pragma unroll
    for (int rt = 0; rt < 4; ++rt)
#pragma unroll
        for (int ct = 0; ct < CT; ++ct) {
            const int col = w * CW + ct * 16 + m;
            const float bv = bias ? bias[r * OUTC + col] : 0.0f;
#pragma unroll
            for (int e = 0; e < 4; ++e) {
                const int row = n0 + rt * 16 + 4 * g + e;
                const float v = acc[rt][ct][e] + bv;
                if constexpr (MODE == 0) {
                    ((float*)outp)[(size_t)row * OUTC + col] = v;
                } else {
                    ((unsigned short*)outp)[((size_t)r * NN + row) * G4 + (size_t)(col & 127) * 4 + (col >> 7)] =
                        f2h_bits(v);
                }
            }
        }
}

// ---------------------------------------------------------------------------
// 16 nodes per block (blockIdx.x), one relation (blockIdx.y). 8 waves; wave w
// owns hidden cols w*16+m across all 4 gate quads (Whh frags in 64 VGPRs).
// Total per-wave state <=128 VGPR -> 4 waves/SIMD = 2 INDEPENDENT blocks/CU,
// so barrier stalls of one block are filled by the other. h double-buffered
// in LDS (XOR-swizzled), 1 barrier/step. Gather prefetched 1 step ahead via
// transposed pre-shifted idx table (one ds_read_b128/step).
// ---------------------------------------------------------------------------
__global__ __launch_bounds__(512, 4) void lstm_kernel(
    const float* __restrict__ x, const int* __restrict__ nbr,
    const float* __restrict__ Whh, const float* __restrict__ fcs,
    const float* __restrict__ fcn, const float* __restrict__ bias,
    const unsigned short* __restrict__ xW, float* __restrict__ Xout)
{
    __shared__ unsigned short h_lds[2][NPB * HD];   // fp16 bits, swizzled
    __shared__ int idx_lds[KST * NPB];              // [t][n], idx<<10 (byte off)

    const int tid = threadIdx.x;
    const int w = tid >> 6, lane = tid & 63;
    const int g = lane >> 4, m = lane & 15;
    const int n0 = blockIdx.x * NPB;
    const int r = blockIdx.y;
    const unsigned laneoff = (unsigned)(w * 16 + m) * 8u;
    const char* xwr = (const char*)(xW + (size_t)r * NN * G4);

    if (tid < KST * NPB) {
        const int t = tid >> 4, n = tid & 15;
        idx_lds[tid] = nbr[((size_t)r * NN + n0 + n) * KST + t] << 10;
    }

    // Whh B-fragments: gate cols q*128 + w*16 + m, resident for all steps
    f16x8 bw[4][4];
    const float* whr = Whh + (size_t)r * G4 * HD;
#pragma unroll
    for (int q = 0; q < 4; ++q)
#pragma unroll
        for (int kc = 0; kc < 4; ++kc)
            bw[q][kc] = load8h(whr + (size_t)(q * 128 + w * 16 + m) * HD + kc * 32 + 8 * g);

    // step-invariant LDS offsets (fp16-element units)
    int rd_off[4], wr_off[4];
#pragma unroll
    for (int kc = 0; kc < 4; ++kc)
        rd_off[kc] = m * HD + ((kc * 32 + 8 * g) ^ ((m & 7) << 3));
#pragma unroll
    for (int e = 0; e < 4; ++e) {
        const int row = 4 * g + e;
        wr_off[e] = row * HD + ((w * 16 + m) ^ ((row & 7) << 3));
    }

    float cst[4] = {0.0f, 0.0f, 0.0f, 0.0f};
    __syncthreads();   // idx_lds ready

    // prefetch step-0 gather (4 gate-quads, 8 B each)
    ushort4 xv[4];
    {
        const int4 i4 = *(const int4*)&idx_lds[4 * g];
        xv[0] = *(const ushort4*)(xwr + (unsigned)i4.x + laneoff);
        xv[1] = *(const ushort4*)(xwr + (unsigned)i4.y + laneoff);
        xv[2] = *(const ushort4*)(xwr + (unsigned)i4.z + laneoff);
        xv[3] = *(const ushort4*)(xwr + (unsigned)i4.w + laneoff);
    }

    int cur = 0;
    for (int t = 0; t < KST; ++t) {
        f32x4 acc[4];
#pragma unroll
        for (int e = 0; e < 4; ++e) {
            acc[0][e] = h2f(xv[e].x);
            acc[1][e] = h2f(xv[e].y);
            acc[2][e] = h2f(xv[e].z);
            acc[3][e] = h2f(xv[e].w);
        }

        if (t + 1 < KST) {   // prefetch next step's gather
            const int4 i4 = *(const int4*)&idx_lds[(t + 1) * 16 + 4 * g];
            xv[0] = *(const ushort4*)(xwr + (unsigned)i4.x + laneoff);
            xv[1] = *(const ushort4*)(xwr + (unsigned)i4.y + laneoff);
            xv[2] = *(const ushort4*)(xwr + (unsigned)i4.z + laneoff);
            xv[3] = *(const ushort4*)(xwr + (unsigned)i4.w + laneoff);
        }

        if (t > 0) {
            const unsigned short* hb = h_lds[cur];
#pragma unroll
            for (int kc = 0; kc < 4; ++kc) {
                const f16x8 a = *(const f16x8*)&hb[rd_off[kc]];
#pragma unroll
                for (int q = 0; q < 4; ++q)
                    acc[q] = mfma16h(a, bw[q][kc], acc[q]);
            }
        }

        // elementwise LSTM cell (i,f,g,o); write h into other buffer
        unsigned short* nh = h_lds[cur ^ 1];
#pragma unroll
        for (int e = 0; e < 4; ++e) {
            const float iv = sigm(acc[0][e]);
            const float fv = sigm(acc[1][e]);
            const float gv = tanh_(acc[2][e]);
            const float ov = sigm(acc[3][e]);
            const float cn = fv * cst[e] + iv * gv;
            cst[e] = cn;
            nh[wr_off[e]] = f2h_bits(ov * tanh_(cn));
        }
        __syncthreads();
        cur ^= 1;
    }

    // ---- FC + leaky-relu: wave w -> out cols w*16+m, rows = 16 nodes
    {
        const unsigned short* hb = h_lds[cur];
        const float* fsr = fcs + (size_t)r * HD * HD;
        const float* fnr = fcn + (size_t)r * HD * HD;
        const int col = w * 16 + m;
        f32x4 oacc = f4splat(bias[r * HD + col]);
#pragma unroll
        for (int kc = 0; kc < 4; ++kc) {
            const f16x8 ax = load8h(x + (size_t)(n0 + m) * HD + kc * 32 + 8 * g);
            const f16x8 ah = *(const f16x8*)&hb[rd_off[kc]];
            const f16x8 bs = load8h(fsr + (size_t)col * HD + kc * 32 + 8 * g);
            const f16x8 bn = load8h(fnr + (size_t)col * HD + kc * 32 + 8 * g);
            oacc = mfma16h(ax, bs, oacc);
            oacc = mfma16h(ah, bn, oacc);
        }
#pragma unroll
        for (int e = 0; e < 4; ++e) {
            const int row = 4 * g + e;
            float v = oacc[e];
            v = v > 0.0f ? v : 0.01f * v;
            Xout[((size_t)(n0 + row) * NRELS + r) * HD + col] = v;
        }
    }
}

// ---------------------------------------------------------------------------
// attention: one wave per node; softmax over 3 relations, f32 throughout
// ---------------------------------------------------------------------------
__global__ __launch_bounds__(256) void attn_kernel(
    const float* __restrict__ X, const float* __restrict__ tc,
    float* __restrict__ out)
{
    const int wv = blockIdx.x * (blockDim.x >> 6) + (threadIdx.x >> 6);
    const int lane = threadIdx.x & 63;
    if (wv >= NN) return;
    const size_t nb = (size_t)wv;

    const float t0 = tc[nb * HD + lane];
    const float t1 = tc[nb * HD + 64 + lane];
    float x0[3], x1[3], sc[3];
#pragma unroll
    for (int r = 0; r < 3; ++r) {
        x0[r] = X[(nb * 3 + r) * HD + lane];
        x1[r] = X[(nb * 3 + r) * HD + 64 + lane];
        float p = x0[r] * t0 + x1[r] * t1;
#pragma unroll
        for (int off = 32; off >= 1; off >>= 1)
            p += __shfl_xor(p, off, 64);
        sc[r] = p;
    }
    const float mx = fmaxf(sc[0], fmaxf(sc[1], sc[2]));
    const float e0 = __expf(sc[0] - mx), e1 = __expf(sc[1] - mx), e2 = __expf(sc[2] - mx);
    const float inv = __builtin_amdgcn_rcpf(e0 + e1 + e2);
    const float a0 = e0 * inv, a1 = e1 * inv, a2 = e2 * inv;
    out[nb * HD + lane]      = a0 * x0[0] + a1 * x0[1] + a2 * x0[2];
    out[nb * HD + 64 + lane] = a0 * x1[0] + a1 * x1[1] + a2 * x1[2];
}

extern "C" void kernel_launch(void* const* d_in, const int* in_sizes, int n_in,
                              void* d_out, int out_size, void* d_ws, size_t ws_size,
                              hipStream_t stream)
{
    const float* x     = (const float*)d_in[0];
    const float* conn  = (const float*)d_in[1];
    const int*   nbr   = (const int*)d_in[2];
    const float* trans = (const float*)d_in[3];
    const float* Wih   = (const float*)d_in[4];
    const float* Whh   = (const float*)d_in[5];
    const float* blstm = (const float*)d_in[6];
    const float* fcs   = (const float*)d_in[7];
    const float* fcn   = (const float*)d_in[8];
    const float* bias  = (const float*)d_in[9];
    float* out = (float*)d_out;

    // ws carve: xW fp16 [3][N][512] | tc f32 [N][128] | X f32 [N][3][128]
    const size_t XW_B = (size_t)NRELS * NN * G4 * 2;   //  50.3 MB
    const size_t TC_B = (size_t)NN * HD * 4;           //   8.4 MB
    const size_t XO_B = (size_t)NN * NRELS * HD * 4;   //  25.2 MB
    if (ws_size < XW_B + TC_B + XO_B) return;          //  83.9 MB floor

    char* wsb = (char*)d_ws;
    unsigned short* xW = (unsigned short*)wsb;
    float*          tc = (float*)(wsb + XW_B);
    float*          Xo = (float*)(wsb + XW_B + TC_B);

    gemm_rt<512, 1><<<dim3(NN / 64, NRELS), 512, 0, stream>>>(x, Wih, blstm, (void*)xW);
    gemm_rt<128, 0><<<dim3(NN / 64, 1), 512, 0, stream>>>(conn, trans, nullptr, (void*)tc);
    lstm_kernel<<<dim3(NN / NPB, NRELS), 512, 0, stream>>>(x, nbr, Whh, fcs, fcn, bias, xW, Xo);
    attn_kernel<<<dim3(NN / 4), 256, 0, stream>>>(Xo, tc, out);
}

// Round 7
// 333.473 us; speedup vs baseline: 1.3129x; 1.0028x over previous
//
#include <hip/hip_runtime.h>

#define NN    16384
#define HD    128
#define G4    512
#define KST   16
#define NRELS 3
#define NPB   16   // nodes per lstm block

using f16x8 = __attribute__((ext_vector_type(8))) _Float16;
using f32x4 = __attribute__((ext_vector_type(4))) float;

static __device__ __forceinline__ f32x4 f4splat(float v) {
    f32x4 r; r[0] = v; r[1] = v; r[2] = v; r[3] = v; return r;
}
static __device__ __forceinline__ f16x8 load8h(const float* p) {
    const float4 a = ((const float4*)p)[0];
    const float4 b = ((const float4*)p)[1];
    f16x8 r;
    r[0] = (_Float16)a.x; r[1] = (_Float16)a.y; r[2] = (_Float16)a.z; r[3] = (_Float16)a.w;
    r[4] = (_Float16)b.x; r[5] = (_Float16)b.y; r[6] = (_Float16)b.z; r[7] = (_Float16)b.w;
    return r;
}
static __device__ __forceinline__ f32x4 mfma16h(f16x8 a, f16x8 b, f32x4 c) {
    return __builtin_amdgcn_mfma_f32_16x16x32_f16(a, b, c, 0, 0, 0);
}
static __device__ __forceinline__ unsigned short f2h_bits(float f) {
    return __builtin_bit_cast(unsigned short, (_Float16)f);
}
static __device__ __forceinline__ float h2f(unsigned short b) {
    return (float)__builtin_bit_cast(_Float16, b);
}
static __device__ __forceinline__ float sigm(float x) {
    return __builtin_amdgcn_rcpf(1.0f + __expf(-x));
}
static __device__ __forceinline__ float tanh_(float x) {
    return 2.0f * __builtin_amdgcn_rcpf(1.0f + __expf(-2.0f * x)) - 1.0f;
}
// Barrier that drains ONLY LDS ops (lgkmcnt) — global prefetch loads stay in
// flight across it (unlike __syncthreads, which emits s_waitcnt vmcnt(0) and
// exposes gather latency every step). All global loads in lstm_kernel are
// consumed by the issuing wave, so skipping the vmcnt drain is safe.
static __device__ __forceinline__ void barrier_lgkm() {
    asm volatile("s_waitcnt lgkmcnt(0)" ::: "memory");
    __builtin_amdgcn_s_barrier();
}

// ---------------------------------------------------------------------------
// C[row,col] = A[row,:] @ W[r][col,:]^T (+bias[r][col]); fp16 inputs, f32 acc.
// MODE 0: f32 out [row*OUTC+col]            (tc = conn @ trans.T)
// MODE 1: fp16-bits out, gate-quad packed   (xW = x @ W_ih.T + b_lstm)
//         quad offset = (r*NN+row)*512 + (col&127)*4 + (col>>7)
// ---------------------------------------------------------------------------
template <int OUTC, int MODE>
__global__ __launch_bounds__(512, 2) void gemm_rt(
    const float* __restrict__ A, const float* __restrict__ W,
    const float* __restrict__ bias, void* __restrict__ outp)
{
    constexpr int CW = OUTC / 8;
    constexpr int CT = CW / 16;
    const int tid = threadIdx.x;
    const int w = tid >> 6, lane = tid & 63;
    const int g = lane >> 4, m = lane & 15;
    const int n0 = blockIdx.x * 64;
    const int r = blockIdx.y;
    const float* Wr = W + (size_t)r * OUTC * HD;

    f32x4 acc[4][CT];
#pragma unroll
    for (int rt = 0; rt < 4; ++rt)
#pragma unroll
        for (int ct = 0; ct < CT; ++ct) acc[rt][ct] = f4splat(0.0f);

#pragma unroll
    for (int kc = 0; kc < 4; ++kc) {
        f16x8 a[4];
#pragma unroll
        for (int rt = 0; rt < 4; ++rt)
            a[rt] = load8h(A + (size_t)(n0 + rt * 16 + m) * HD + kc * 32 + 8 * g);
        f16x8 b[CT];
#pragma unroll
        for (int ct = 0; ct < CT; ++ct)
            b[ct] = load8h(Wr + (size_t)(w * CW + ct * 16 + m) * HD + kc * 32 + 8 * g);
#pragma unroll
        for (int rt = 0; rt < 4; ++rt)
#pragma unroll
            for (int ct = 0; ct < CT; ++ct)
                acc[rt][ct] = mfma16h(a[rt], b[ct], acc[rt][ct]);
    }

#pragma unroll
    for (int rt = 0; rt < 4; ++rt)
#pragma unroll
        for (int ct = 0; ct < CT; ++ct) {
            const int col = w * CW + ct * 16 + m;
            const float bv = bias ? bias[r * OUTC + col] : 0.0f;
#pragma unroll
            for (int e = 0; e < 4; ++e) {
                const int row = n0 + rt * 16 + 4 * g + e;
                const float v = acc[rt][ct][e] + bv;
                if constexpr (MODE == 0) {
                    ((float*)outp)[(size_t)row * OUTC + col] = v;
                } else {
                    ((unsigned short*)outp)[((size_t)r * NN + row) * G4 + (size_t)(col & 127) * 4 + (col >> 7)] =
                        f2h_bits(v);
                }
            }
        }
}

// ---------------------------------------------------------------------------
// 16 nodes per block (blockIdx.x), one relation (blockIdx.y). 8 waves; wave w
// owns hidden cols w*16+m across all 4 gate quads (Whh frags in 64 VGPRs).
// 4 waves/SIMD = 2 independent blocks/CU. h double-buffered in LDS
// (XOR-swizzled), ONE lgkm-only barrier per step: gather prefetch loads stay
// in flight across the barrier (vmcnt not drained).
// ---------------------------------------------------------------------------
__global__ __launch_bounds__(512, 4) void lstm_kernel(
    const float* __restrict__ x, const int* __restrict__ nbr,
    const float* __restrict__ Whh, const float* __restrict__ fcs,
    const float* __restrict__ fcn, const float* __restrict__ bias,
    const unsigned short* __restrict__ xW, float* __restrict__ Xout)
{
    __shared__ unsigned short h_lds[2][NPB * HD];   // fp16 bits, swizzled
    __shared__ int idx_lds[KST * NPB];              // [t][n], idx<<10 (byte off)

    const int tid = threadIdx.x;
    const int w = tid >> 6, lane = tid & 63;
    const int g = lane >> 4, m = lane & 15;
    const int n0 = blockIdx.x * NPB;
    const int r = blockIdx.y;
    const unsigned laneoff = (unsigned)(w * 16 + m) * 8u;
    const char* xwr = (const char*)(xW + (size_t)r * NN * G4);

    if (tid < KST * NPB) {
        const int t = tid >> 4, n = tid & 15;
        idx_lds[tid] = nbr[((size_t)r * NN + n0 + n) * KST + t] << 10;
    }

    // Whh B-fragments: gate cols q*128 + w*16 + m, resident for all steps
    f16x8 bw[4][4];
    const float* whr = Whh + (size_t)r * G4 * HD;
#pragma unroll
    for (int q = 0; q < 4; ++q)
#pragma unroll
        for (int kc = 0; kc < 4; ++kc)
            bw[q][kc] = load8h(whr + (size_t)(q * 128 + w * 16 + m) * HD + kc * 32 + 8 * g);

    // step-invariant LDS offsets (fp16-element units)
    int rd_off[4], wr_off[4];
#pragma unroll
    for (int kc = 0; kc < 4; ++kc)
        rd_off[kc] = m * HD + ((kc * 32 + 8 * g) ^ ((m & 7) << 3));
#pragma unroll
    for (int e = 0; e < 4; ++e) {
        const int row = 4 * g + e;
        wr_off[e] = row * HD + ((w * 16 + m) ^ ((row & 7) << 3));
    }

    float cst[4] = {0.0f, 0.0f, 0.0f, 0.0f};
    barrier_lgkm();   // idx_lds ready

    // prefetch step-0 gather (4 gate-quads, 8 B each)
    ushort4 xv[4];
    {
        const int4 i4 = *(const int4*)&idx_lds[4 * g];
        xv[0] = *(const ushort4*)(xwr + (unsigned)i4.x + laneoff);
        xv[1] = *(const ushort4*)(xwr + (unsigned)i4.y + laneoff);
        xv[2] = *(const ushort4*)(xwr + (unsigned)i4.z + laneoff);
        xv[3] = *(const ushort4*)(xwr + (unsigned)i4.w + laneoff);
    }

    int cur = 0;
    for (int t = 0; t < KST; ++t) {
        f32x4 acc[4];
#pragma unroll
        for (int e = 0; e < 4; ++e) {
            acc[0][e] = h2f(xv[e].x);
            acc[1][e] = h2f(xv[e].y);
            acc[2][e] = h2f(xv[e].z);
            acc[3][e] = h2f(xv[e].w);
        }

        if (t + 1 < KST) {   // prefetch next step's gather (stays in flight
            const int4 i4 = *(const int4*)&idx_lds[(t + 1) * 16 + 4 * g];
            xv[0] = *(const ushort4*)(xwr + (unsigned)i4.x + laneoff);   // across
            xv[1] = *(const ushort4*)(xwr + (unsigned)i4.y + laneoff);   // the
            xv[2] = *(const ushort4*)(xwr + (unsigned)i4.z + laneoff);   // lgkm
            xv[3] = *(const ushort4*)(xwr + (unsigned)i4.w + laneoff);   // barrier)
        }

        if (t > 0) {
            const unsigned short* hb = h_lds[cur];
#pragma unroll
            for (int kc = 0; kc < 4; ++kc) {
                const f16x8 a = *(const f16x8*)&hb[rd_off[kc]];
#pragma unroll
                for (int q = 0; q < 4; ++q)
                    acc[q] = mfma16h(a, bw[q][kc], acc[q]);
            }
        }

        // elementwise LSTM cell (i,f,g,o); write h into other buffer
        unsigned short* nh = h_lds[cur ^ 1];
#pragma unroll
        for (int e = 0; e < 4; ++e) {
            const float iv = sigm(acc[0][e]);
            const float fv = sigm(acc[1][e]);
            const float gv = tanh_(acc[2][e]);
            const float ov = sigm(acc[3][e]);
            const float cn = fv * cst[e] + iv * gv;
            cst[e] = cn;
            nh[wr_off[e]] = f2h_bits(ov * tanh_(cn));
        }
        barrier_lgkm();   // h visible; vmcnt (prefetch) NOT drained
        cur ^= 1;
    }

    // ---- FC + leaky-relu: wave w -> out cols w*16+m, rows = 16 nodes
    {
        const unsigned short* hb = h_lds[cur];
        const float* fsr = fcs + (size_t)r * HD * HD;
        const float* fnr = fcn + (size_t)r * HD * HD;
        const int col = w * 16 + m;
        f32x4 oacc = f4splat(bias[r * HD + col]);
#pragma unroll
        for (int kc = 0; kc < 4; ++kc) {
            const f16x8 ax = load8h(x + (size_t)(n0 + m) * HD + kc * 32 + 8 * g);
            const f16x8 ah = *(const f16x8*)&hb[rd_off[kc]];
            const f16x8 bs = load8h(fsr + (size_t)col * HD + kc * 32 + 8 * g);
            const f16x8 bn = load8h(fnr + (size_t)col * HD + kc * 32 + 8 * g);
            oacc = mfma16h(ax, bs, oacc);
            oacc = mfma16h(ah, bn, oacc);
        }
#pragma unroll
        for (int e = 0; e < 4; ++e) {
            const int row = 4 * g + e;
            float v = oacc[e];
            v = v > 0.0f ? v : 0.01f * v;
            Xout[((size_t)(n0 + row) * NRELS + r) * HD + col] = v;
        }
    }
}

// ---------------------------------------------------------------------------
// attention: one wave per node; softmax over 3 relations, f32 throughout
// ---------------------------------------------------------------------------
__global__ __launch_bounds__(256) void attn_kernel(
    const float* __restrict__ X, const float* __restrict__ tc,
    float* __restrict__ out)
{
    const int wv = blockIdx.x * (blockDim.x >> 6) + (threadIdx.x >> 6);
    const int lane = threadIdx.x & 63;
    if (wv >= NN) return;
    const size_t nb = (size_t)wv;

    const float t0 = tc[nb * HD + lane];
    const float t1 = tc[nb * HD + 64 + lane];
    float x0[3], x1[3], sc[3];
#pragma unroll
    for (int r = 0; r < 3; ++r) {
        x0[r] = X[(nb * 3 + r) * HD + lane];
        x1[r] = X[(nb * 3 + r) * HD + 64 + lane];
        float p = x0[r] * t0 + x1[r] * t1;
#pragma unroll
        for (int off = 32; off >= 1; off >>= 1)
            p += __shfl_xor(p, off, 64);
        sc[r] = p;
    }
    const float mx = fmaxf(sc[0], fmaxf(sc[1], sc[2]));
    const float e0 = __expf(sc[0] - mx), e1 = __expf(sc[1] - mx), e2 = __expf(sc[2] - mx);
    const float inv = __builtin_amdgcn_rcpf(e0 + e1 + e2);
    const float a0 = e0 * inv, a1 = e1 * inv, a2 = e2 * inv;
    out[nb * HD + lane]      = a0 * x0[0] + a1 * x0[1] + a2 * x0[2];
    out[nb * HD + 64 + lane] = a0 * x1[0] + a1 * x1[1] + a2 * x1[2];
}

extern "C" void kernel_launch(void* const* d_in, const int* in_sizes, int n_in,
                              void* d_out, int out_size, void* d_ws, size_t ws_size,
                              hipStream_t stream)
{
    const float* x     = (const float*)d_in[0];
    const float* conn  = (const float*)d_in[1];
    const int*   nbr   = (const int*)d_in[2];
    const float* trans = (const float*)d_in[3];
    const float* Wih   = (const float*)d_in[4];
    const float* Whh   = (const float*)d_in[5];
    const float* blstm = (const float*)d_in[6];
    const float* fcs   = (const float*)d_in[7];
    const float* fcn   = (const float*)d_in[8];
    const float* bias  = (const float*)d_in[9];
    float* out = (float*)d_out;

    // ws carve: xW fp16 [3][N][512] | tc f32 [N][128] | X f32 [N][3][128]
    const size_t XW_B = (size_t)NRELS * NN * G4 * 2;   //  50.3 MB
    const size_t TC_B = (size_t)NN * HD * 4;           //   8.4 MB
    const size_t XO_B = (size_t)NN * NRELS * HD * 4;   //  25.2 MB
    if (ws_size < XW_B + TC_B + XO_B) return;          //  83.9 MB floor

    char* wsb = (char*)d_ws;
    unsigned short* xW = (unsigned short*)wsb;
    float*          tc = (float*)(wsb + XW_B);
    float*          Xo = (float*)(wsb + XW_B + TC_B);

    gemm_rt<512, 1><<<dim3(NN / 64, NRELS), 512, 0, stream>>>(x, Wih, blstm, (void*)xW);
    gemm_rt<128, 0><<<dim3(NN / 64, 1), 512, 0, stream>>>(conn, trans, nullptr, (void*)tc);
    lstm_kernel<<<dim3(NN / NPB, NRELS), 512, 0, stream>>>(x, nbr, Whh, fcs, fcn, bias, xW, Xo);
    attn_kernel<<<dim3(NN / 4), 256, 0, stream>>>(Xo, tc, out);
}